// Round 1
// baseline (124.229 us; speedup 1.0000x reference)
//
#include <hip/hip_runtime.h>
#include <math.h>

#define N1 8192
#define N2 8192
#define NBATCH 2
#define KNN 16

// Pack p1 = xyz1 + flow1 as float4(x, y, z, |p1|^2), and f1 as float4(fx, fy, fz, 0).
__global__ __launch_bounds__(256) void pw3_prep_kernel(
    const float* __restrict__ xyz1,
    const float* __restrict__ flow1,
    float4* __restrict__ p1p,
    float4* __restrict__ f1p) {
  int i = blockIdx.x * blockDim.x + threadIdx.x;  // 0 .. B*N1-1
  if (i >= NBATCH * N1) return;
  int b = i >> 13;            // / N1
  int m = i & (N1 - 1);
  const float* x1 = xyz1 + b * 3 * N1;
  const float* f1 = flow1 + b * 3 * N1;
  float fx = f1[m], fy = f1[N1 + m], fz = f1[2 * N1 + m];
  float px = x1[m] + fx;
  float py = x1[N1 + m] + fy;
  float pz = x1[2 * N1 + m] + fz;
  float n1 = (px * px + py * py) + pz * pz;   // match reference (p1*p1).sum(-1)
  p1p[i] = make_float4(px, py, pz, n1);
  f1p[i] = make_float4(fx, fy, fz, 0.0f);
}

// One wave (64 lanes) per query point. Running top-16 (dist, idx) lives
// distributed in lanes 0..15, sorted ascending (lane 15 = current k-th dist).
__global__ __launch_bounds__(256) void pw3_knn_kernel(
    const float* __restrict__ xyz2,
    const float4* __restrict__ p1p,
    const float4* __restrict__ f1p,
    float* __restrict__ out) {
  int gtid = blockIdx.x * blockDim.x + threadIdx.x;
  int wave = gtid >> 6;          // global wave id = query id, 0 .. B*N2-1
  int lane = threadIdx.x & 63;
  int b = wave >> 13;            // / N2
  int n = wave & (N2 - 1);

  const float* x2 = xyz2 + b * 3 * N2;
  float qx = x2[n];
  float qy = x2[N2 + n];
  float qz = x2[2 * N2 + n];
  float n2 = (qx * qx + qy * qy) + qz * qz;   // match reference (p2*p2).sum(-1)

  const float4* __restrict__ src = p1p + b * N1;

  float val = INFINITY;   // lanes 0..15: sorted top-16 distances
  int   vidx = 0;         // matching source indices
  float kth = INFINITY;   // broadcast copy of val at lane 15

  #pragma unroll 1
  for (int c = 0; c < N1 / 64; ++c) {
    int base = c * 64;
    float4 s = src[base + lane];
    float dot = (s.x * qx + s.y * qy) + s.z * qz;
    float d = (n2 - 2.0f * dot) + s.w;        // reference expansion order

    unsigned long long bal = __ballot(d < kth);
    if (bal) {
      do {
        int l = __ffsll(bal) - 1;
        bal &= bal - 1;
        float cd = __shfl(d, l);              // candidate dist (uniform src lane)
        int   ci = base + l;                  // candidate index (scalar)
        // insert into the distributed sorted list (self-filtering if cd >= val[15])
        float pv = __shfl_up(val, 1);
        int   pi = __shfl_up(vidx, 1);
        bool lt  = cd < val;
        bool ltp = (lane > 0) && (cd < pv);
        val  = lt ? (ltp ? pv : cd) : val;
        vidx = lt ? (ltp ? pi : ci) : vidx;
      } while (bal);
      kth = __shfl(val, 15);
    }
  }

  // Gather the 16 selected flows (lanes 0..15) and sum across the 16-lane group.
  float fx = 0.0f, fy = 0.0f, fz = 0.0f;
  if (lane < 16) {
    float4 f = f1p[b * N1 + vidx];
    fx = f.x; fy = f.y; fz = f.z;
  }
  #pragma unroll
  for (int o = 8; o > 0; o >>= 1) {
    fx += __shfl_xor(fx, o);
    fy += __shfl_xor(fy, o);
    fz += __shfl_xor(fz, o);
  }

  if (lane == 0) {
    float* op = out + b * 3 * N2;
    const float inv_k = 1.0f / KNN;
    op[n]          = qx - fx * inv_k;
    op[N2 + n]     = qy - fy * inv_k;
    op[2 * N2 + n] = qz - fz * inv_k;
  }
}

extern "C" void kernel_launch(void* const* d_in, const int* in_sizes, int n_in,
                              void* d_out, int out_size, void* d_ws, size_t ws_size,
                              hipStream_t stream) {
  const float* xyz1  = (const float*)d_in[0];
  const float* xyz2  = (const float*)d_in[1];
  const float* flow1 = (const float*)d_in[2];
  // d_in[3] is K; fixed at 16 for this problem.
  float* out = (float*)d_out;

  float4* p1p = (float4*)d_ws;                       // B*N1 float4 = 512 KB total with f1p
  float4* f1p = (float4*)((char*)d_ws + (size_t)NBATCH * N1 * sizeof(float4));

  {
    int total = NBATCH * N1;
    int threads = 256;
    int blocks = (total + threads - 1) / threads;
    pw3_prep_kernel<<<blocks, threads, 0, stream>>>(xyz1, flow1, p1p, f1p);
  }
  {
    int total_waves = NBATCH * N2;        // one wave per query
    int threads = 256;                    // 4 waves per block
    int blocks = total_waves * 64 / threads;
    pw3_knn_kernel<<<blocks, threads, 0, stream>>>(xyz2, p1p, f1p, out);
  }
}